// Round 4
// baseline (1463.052 us; speedup 1.0000x reference)
//
#include <hip/hip_runtime.h>
#include <hip/hip_bf16.h>

// AWQ int4 GEMM: out[8192,12288](f32) = x[8192,4096](f32) * dequant(qweight) + bias
// Device dtype contract: reference f16 tensors are presented as FLOAT32.
// Unpack order [0,4,1,5,2,6,3,7]: element i of a packed dword has shift
// sh(i) = (i>>1)*4 + (i&1)*16.
//
// 3-pass (needs ws >= 160 MiB): x->bf16, qweight->W^T bf16, bf16 MFMA GEMM.
// Fallback: fused kernel (f32 A reg-staged + in-loop dequant).

#define M_DIM 8192
#define K_DIM 4096
#define N_DIM 12288
#define N8    1536
#define BM    128
#define BN    128
#define BK    64
#define GM    (M_DIM / BM) // 64
#define GN    (N_DIM / BN) // 96

typedef short bf16x8 __attribute__((ext_vector_type(8)));   // 8 bf16 (4 VGPRs)
typedef float f32x4 __attribute__((ext_vector_type(4)));

__device__ __forceinline__ unsigned short f32_to_bf16u(float f) {
  __hip_bfloat16 b = __float2bfloat16(f);
  return __builtin_bit_cast(unsigned short, b);
}
__device__ __forceinline__ unsigned pack2bf(float a, float b) {
  return (unsigned)f32_to_bf16u(a) | ((unsigned)f32_to_bf16u(b) << 16);
}

__device__ __forceinline__ void load_lds16(const void* g, void* l) {
  __builtin_amdgcn_global_load_lds(
      (const __attribute__((address_space(1))) void*)g,
      (__attribute__((address_space(3))) void*)l, 16, 0, 0);
}

// ---------------- pass 1: x f32 -> bf16 ----------------
__global__ __launch_bounds__(256) void cvt_x_kernel(
    const float* __restrict__ X, unsigned short* __restrict__ XB) {
  size_t i = (size_t)(blockIdx.x * 256 + threadIdx.x) * 8;
  float4 a = *(const float4*)(X + i);
  float4 b = *(const float4*)(X + i + 4);
  uint4 o = make_uint4(pack2bf(a.x, a.y), pack2bf(a.z, a.w),
                       pack2bf(b.x, b.y), pack2bf(b.z, b.w));
  *(uint4*)(XB + i) = o;
}

// ---------------- pass 2: dequant qweight -> W^T [N][K] bf16 ----------------
__global__ __launch_bounds__(256) void dequant_kernel(
    const int* __restrict__ QW, const int* __restrict__ QZ,
    const float* __restrict__ SC, unsigned short* __restrict__ WT) {
  __shared__ unsigned short T[32][128]; // [k][n], 8 KB
  const int kb = blockIdx.x & 127;  // K/32
  const int nb = blockIdx.x >> 7;   // N/128
  const int k0 = kb * 32, n0c = nb * 128;
  const int g = k0 >> 7;
  const int tid = threadIdx.x;

#pragma unroll
  for (int j = 0; j < 2; ++j) {
    int d = j * 256 + tid;
    int n8l = d & 15, k = d >> 4;
    int n8g = (n0c >> 3) + n8l;
    unsigned qw = ((const unsigned*)QW)[(size_t)(k0 + k) * N8 + n8g];
    unsigned qz = ((const unsigned*)QZ)[(size_t)g * N8 + n8g];
    float4 s0 = *(const float4*)(SC + (size_t)g * N_DIM + n0c + n8l * 8);
    float4 s1 = *(const float4*)(SC + (size_t)g * N_DIM + n0c + n8l * 8 + 4);
    float sa[8] = {s0.x, s0.y, s0.z, s0.w, s1.x, s1.y, s1.z, s1.w};
    float v[8];
#pragma unroll
    for (int i = 0; i < 8; ++i) {
      int sh = ((i >> 1) << 2) + ((i & 1) << 4);
      float qf = (float)((qw >> sh) & 15u);
      float zf = (float)((qz >> sh) & 15u);
      v[i] = (qf - zf) * sa[i];
    }
    uint4 o = make_uint4(pack2bf(v[0], v[1]), pack2bf(v[2], v[3]),
                         pack2bf(v[4], v[5]), pack2bf(v[6], v[7]));
    *(uint4*)&T[k][n8l * 8] = o;
  }
  __syncthreads();
#pragma unroll
  for (int p = 0; p < 2; ++p) {
    int c = p * 256 + tid;
    int n = c >> 2, seg = c & 3;
    unsigned short u[8];
#pragma unroll
    for (int j = 0; j < 8; ++j) u[j] = T[seg * 8 + j][n];
    uint4 o = make_uint4((unsigned)u[0] | ((unsigned)u[1] << 16),
                         (unsigned)u[2] | ((unsigned)u[3] << 16),
                         (unsigned)u[4] | ((unsigned)u[5] << 16),
                         (unsigned)u[6] | ((unsigned)u[7] << 16));
    *(uint4*)(WT + (size_t)(n0c + n) * K_DIM + k0 + seg * 8) = o;
  }
}

// ---------------- pass 3: bf16 GEMM (XB [M][K], WT [N][K]) ----------------
__global__ __launch_bounds__(256, 2) void gemm_pre_kernel(
    const unsigned short* __restrict__ XB, const unsigned short* __restrict__ WT,
    const float* __restrict__ BIAS, float* __restrict__ OUT) {
  __shared__ __attribute__((aligned(16))) unsigned char As[BM * BK * 2]; // 16 KB
  __shared__ __attribute__((aligned(16))) unsigned char Bs[BN * BK * 2]; // 16 KB

  const int tid = threadIdx.x;
  const int lane = tid & 63;
  const int w = tid >> 6;
  const int wm = w >> 1;
  const int wn = w & 1;
  const int l15 = lane & 15;
  const int lhi = lane >> 4;

  const int bid = blockIdx.x;
  const int swz = (bid & 7) * (GM * GN / 8) + (bid >> 3); // bijective, 6144%8==0
  const int bm = swz & (GM - 1);
  const int bn = swz >> 6;
  const int m0 = bm * BM;
  const int n0 = bn * BN;

  // linear LDS dest + pre-swizzled global source (rule #21)
  // LDS byte b holds row r=b>>7, kbyte = (b&127) ^ ((r&7)<<4)
  int rowA[4], rowB[4], colk[4], dst[4];
#pragma unroll
  for (int q = 0; q < 4; ++q) {
    int b = q * 4096 + tid * 16;
    int r = b >> 7;
    int cbo = (b & 127) ^ ((r & 7) << 4);
    rowA[q] = m0 + r;
    rowB[q] = n0 + r;
    colk[q] = cbo >> 1;
    dst[q] = b;
  }

  f32x4 acc[4][4] = {};

  for (int kt = 0; kt < K_DIM / BK; ++kt) {
    const int k0 = kt * BK;
#pragma unroll
    for (int q = 0; q < 4; ++q)
      load_lds16(XB + (size_t)rowA[q] * K_DIM + colk[q] + k0, As + dst[q]);
#pragma unroll
    for (int q = 0; q < 4; ++q)
      load_lds16(WT + (size_t)rowB[q] * K_DIM + colk[q] + k0, Bs + dst[q]);

    __syncthreads(); // vmcnt drained by compiler before barrier

#pragma unroll
    for (int kk = 0; kk < 2; ++kk) {
      bf16x8 af[4], bf[4];
#pragma unroll
      for (int mi = 0; mi < 4; ++mi) {
        int m = wm * 64 + mi * 16 + l15;
        int addr = (m * BK + kk * 32 + 8 * lhi) * 2;
        addr ^= ((m & 7) << 4);
        af[mi] = *(const bf16x8*)(As + addr);
      }
#pragma unroll
      for (int ni = 0; ni < 4; ++ni) {
        int n = wn * 64 + ni * 16 + l15;
        int addr = (n * BK + kk * 32 + 8 * lhi) * 2;
        addr ^= ((n & 7) << 4);
        bf[ni] = *(const bf16x8*)(Bs + addr);
      }
#pragma unroll
      for (int mi = 0; mi < 4; ++mi)
#pragma unroll
        for (int ni = 0; ni < 4; ++ni)
          acc[mi][ni] = __builtin_amdgcn_mfma_f32_16x16x32_bf16(
              af[mi], bf[ni], acc[mi][ni], 0, 0, 0);
    }

    __syncthreads();
  }

  // D layout: col=lane&15, row=4*(lane>>4)+e (measured m89/m91)
#pragma unroll
  for (int ni = 0; ni < 4; ++ni) {
    int col = n0 + wn * 64 + ni * 16 + l15;
    float bv = BIAS[col];
#pragma unroll
    for (int mi = 0; mi < 4; ++mi) {
      int row = m0 + wm * 64 + mi * 16 + lhi * 4;
#pragma unroll
      for (int e = 0; e < 4; ++e)
        OUT[(size_t)(row + e) * N_DIM + col] = acc[mi][ni][e] + bv;
    }
  }
}

// ---------------- fallback: fused kernel (small ws) ----------------
__global__ __launch_bounds__(256, 2) void gemm_fused_kernel(
    const float* __restrict__ X, const int* __restrict__ QW,
    const int* __restrict__ QZ, const float* __restrict__ SC,
    const float* __restrict__ BIAS, float* __restrict__ OUT) {
  __shared__ __attribute__((aligned(16))) unsigned char As[BM * BK * 2];
  __shared__ __attribute__((aligned(16))) unsigned char Bs[BN * BK * 2];

  const int tid = threadIdx.x;
  const int lane = tid & 63;
  const int w = tid >> 6;
  const int wm = w >> 1;
  const int wn = w & 1;
  const int l15 = lane & 15;
  const int lhi = lane >> 4;

  const int bid = blockIdx.x;
  const int swz = (bid & 7) * (GM * GN / 8) + (bid >> 3);
  const int bm = swz & (GM - 1);
  const int bn = swz >> 6;
  const int m0 = bm * BM;
  const int n0 = bn * BN;

  // A reg-staging plan: q-th chunk: row r=q*16+(t>>4), kf=(t&15)*4 (floats)
  const int thi = tid >> 4, tlo = tid & 15;
  const int n8l = tid & 15;
  const int krow = (tid >> 4) * 4;
  const int n8g = (n0 >> 3) + n8l;

  f32x4 acc[4][4] = {};

  for (int kt = 0; kt < K_DIM / BK; ++kt) {
    const int k0 = kt * BK;
    const int g = k0 >> 7;

    // A: load f32, cvt bf16, swizzled LDS write
    float4 xa[8];
#pragma unroll
    for (int q = 0; q < 8; ++q) {
      int r = q * 16 + thi;
      xa[q] = *(const float4*)(X + (size_t)(m0 + r) * K_DIM + k0 + tlo * 4);
    }

    // B: load packed, dequant f32, swizzled transposed LDS write
    unsigned qw[4];
#pragma unroll
    for (int j = 0; j < 4; ++j)
      qw[j] = ((const unsigned*)QW)[(size_t)(k0 + krow + j) * N8 + n8g];
    const unsigned qz = ((const unsigned*)QZ)[(size_t)g * N8 + n8g];
    float4 s0 = *(const float4*)(SC + (size_t)g * N_DIM + n0 + n8l * 8);
    float4 s1 = *(const float4*)(SC + (size_t)g * N_DIM + n0 + n8l * 8 + 4);
    float sa[8] = {s0.x, s0.y, s0.z, s0.w, s1.x, s1.y, s1.z, s1.w};

#pragma unroll
    for (int q = 0; q < 8; ++q) {
      int r = q * 16 + thi;
      int addr = r * 128 + ((tlo * 8) ^ ((r & 7) << 4));
      *(uint2*)(As + addr) =
          make_uint2(pack2bf(xa[q].x, xa[q].y), pack2bf(xa[q].z, xa[q].w));
    }
#pragma unroll
    for (int i = 0; i < 8; ++i) {
      int sh = ((i >> 1) << 2) + ((i & 1) << 4);
      float zf = (float)((qz >> sh) & 15u);
      float nzs = -zf * sa[i];
      unsigned short h[4];
#pragma unroll
      for (int j = 0; j < 4; ++j) {
        float qf = (float)((qw[j] >> sh) & 15u);
        h[j] = f32_to_bf16u(fmaf(qf, sa[i], nzs));
      }
      int n = n8l * 8 + i;
      int addr = (n * BK + krow) * 2;
      addr ^= (((n & 7) ^ ((n >> 3) & 7)) << 4);
      *(uint2*)(Bs + addr) = make_uint2((unsigned)h[0] | ((unsigned)h[1] << 16),
                                        (unsigned)h[2] | ((unsigned)h[3] << 16));
    }

    __syncthreads();

#pragma unroll
    for (int kk = 0; kk < 2; ++kk) {
      bf16x8 af[4], bf[4];
#pragma unroll
      for (int mi = 0; mi < 4; ++mi) {
        int m = wm * 64 + mi * 16 + l15;
        int addr = (m * BK + kk * 32 + 8 * lhi) * 2;
        addr ^= ((m & 7) << 4);
        af[mi] = *(const bf16x8*)(As + addr);
      }
#pragma unroll
      for (int ni = 0; ni < 4; ++ni) {
        int n = wn * 64 + ni * 16 + l15;
        int addr = (n * BK + kk * 32 + 8 * lhi) * 2;
        addr ^= (((n & 7) ^ ((n >> 3) & 7)) << 4);
        bf[ni] = *(const bf16x8*)(Bs + addr);
      }
#pragma unroll
      for (int mi = 0; mi < 4; ++mi)
#pragma unroll
        for (int ni = 0; ni < 4; ++ni)
          acc[mi][ni] = __builtin_amdgcn_mfma_f32_16x16x32_bf16(
              af[mi], bf[ni], acc[mi][ni], 0, 0, 0);
    }

    __syncthreads();
  }

#pragma unroll
  for (int ni = 0; ni < 4; ++ni) {
    int col = n0 + wn * 64 + ni * 16 + l15;
    float bv = BIAS[col];
#pragma unroll
    for (int mi = 0; mi < 4; ++mi) {
      int row = m0 + wm * 64 + mi * 16 + lhi * 4;
#pragma unroll
      for (int e = 0; e < 4; ++e)
        OUT[(size_t)(row + e) * N_DIM + col] = acc[mi][ni][e] + bv;
    }
  }
}

extern "C" void kernel_launch(void* const* d_in, const int* in_sizes, int n_in,
                              void* d_out, int out_size, void* d_ws, size_t ws_size,
                              hipStream_t stream) {
  const float* X = (const float*)d_in[0];
  const int* QW = (const int*)d_in[1];
  const int* QZ = (const int*)d_in[2];
  const float* SC = (const float*)d_in[3];
  const float* BIAS = (const float*)d_in[4];
  float* OUT = (float*)d_out;
  (void)in_sizes; (void)n_in; (void)out_size;

  const size_t xb_elems = (size_t)M_DIM * K_DIM;          // 33,554,432
  const size_t wt_elems = (size_t)N_DIM * K_DIM;          // 50,331,648
  const size_t need = (xb_elems + wt_elems) * 2;          // 167,772,160 B

  if (ws_size >= need) {
    unsigned short* XB = (unsigned short*)d_ws;
    unsigned short* WT = XB + xb_elems;
    cvt_x_kernel<<<dim3(M_DIM * K_DIM / 8 / 256), 256, 0, stream>>>(X, XB);
    dequant_kernel<<<dim3((K_DIM / 32) * (N_DIM / 128)), 256, 0, stream>>>(QW, QZ, SC, WT);
    gemm_pre_kernel<<<dim3(GM * GN), 256, 0, stream>>>(XB, WT, BIAS, OUT);
  } else {
    gemm_fused_kernel<<<dim3(GM * GN), 256, 0, stream>>>(X, QW, QZ, SC, BIAS, OUT);
  }
}